// Round 5
// baseline (89.155 us; speedup 1.0000x reference)
//
#include <hip/hip_runtime.h>
#include <math.h>

// Rational-quadratic spline, K=8 bins, tail B=3.
// R5: persistent blocks (768 = 3/CU), double-buffered LDS staging with
//     counted s_waitcnt vmcnt(7) + raw barriers (T3/T4 minimal 2-phase):
//     next tile's global_load_lds stay in flight while computing current.
//     x folded into the staged stream; uniform 7 vm-ops/thread/tile so the
//     vmcnt arithmetic is exact. Nontemporal out stores. Per-thread ldv
//     accumulator -> one block reduction at block end.

#define TAILB 3.0f
#define MINSZ 0.001f
#define NBLOCKS 768
#define NTILES 16384          // 4194304 / 256
#define TILE_F4 1600          // params float4 per tile
#define BUF_F4 1664           // + 64 float4 of x
#define BUF_F 6656            // floats per buffer

typedef unsigned int u32;

__device__ __forceinline__ void gload_lds16(const void* g, void* l) {
    __builtin_amdgcn_global_load_lds(
        (const __attribute__((address_space(1))) u32*)g,
        (__attribute__((address_space(3))) u32*)l,
        16, 0, 0);
}

__device__ __forceinline__ float frcp(float x) {
    return __builtin_amdgcn_rcpf(x);   // v_rcp_f32, ~1 ulp
}

__device__ __forceinline__ float softplus_d(float u) {
    return fmaxf(u, 0.0f) + __logf(1.0f + __expf(-fabsf(u))) + MINSZ;
}

// Stage one tile (25600 B params + 1024 B x) into ldsbuf.
// Exactly 7 global_load_lds per thread, wave-uniform paths:
//   v=0..5: params chunks q = tid + v*256
//   v=6:    wave0 -> params tail, wave1 -> x, waves2/3 -> idempotent dummy
__device__ __forceinline__ void stage_tile(const float4* __restrict__ params4,
                                           const float4* __restrict__ x4,
                                           float4* ldsbuf, int tile, int tid)
{
    const float4* psrc = params4 + (size_t)tile * TILE_F4;
    #pragma unroll
    for (int v = 0; v < 6; ++v) {
        const int q = tid + v * 256;
        gload_lds16(psrc + q, ldsbuf + q);
    }
    const int q = 1536 + tid;
    if (q < 1600) {                       // wave 0: params chunks 1536..1599
        gload_lds16(psrc + q, ldsbuf + q);
    } else if (q < 1664) {                // wave 1: x chunks 1600..1663
        gload_lds16(x4 + (size_t)tile * 64 + (q - 1600), ldsbuf + q);
    } else {                              // waves 2,3: dummy (same addr, same data)
        gload_lds16(psrc + tid, ldsbuf + tid);
    }
}

__launch_bounds__(256, 3)
__global__ void rqs_kernel(const float* __restrict__ x_in,
                           const float* __restrict__ params,
                           float* __restrict__ out,
                           float* __restrict__ partial)
{
    __shared__ __align__(16) float lds[2 * BUF_F];
    __shared__ float wsum[4];

    const int tid = threadIdx.x;
    const int bid = blockIdx.x;
    const float4* params4 = (const float4*)params;
    const float4* x4 = (const float4*)x_in;
    const float fac_num = (2.0f * TAILB) * (2.0f * TAILB - 8.0f * MINSZ); // 35.952

    float accv = 0.0f;

    // prologue: stage first tile into buf0
    stage_tile(params4, x4, (float4*)lds, bid, tid);

    int k = 0;
    for (int t = bid; t < NTILES; t += NBLOCKS, ++k) {
        const int cur = k & 1;
        // issue next tile's loads into the other buffer (dummy restage of the
        // current tile on the last iteration keeps the vm-op count uniform)
        const int tn = (t + NBLOCKS < NTILES) ? (t + NBLOCKS) : t;
        stage_tile(params4, x4, (float4*)&lds[(cur ^ 1) * BUF_F], tn, tid);

        // wait only for the CURRENT tile's 7 ops (+ drains prev store);
        // the next tile's 7 stay in flight across the barrier.
        asm volatile("s_waitcnt vmcnt(7)" ::: "memory");
        __builtin_amdgcn_s_barrier();

        const float* row = &lds[cur * BUF_F + tid * 25];
        const float x = lds[cur * BUF_F + 6400 + tid];
        const float xi = fminf(fmaxf(x, -TAILB), TAILB);

        // ---- widths: softmax (no max-sub; N(0,1) inputs, fp32-safe) ----
        float ew[8];
        float s = 0.0f;
        #pragma unroll
        for (int j = 0; j < 8; ++j) { ew[j] = __expf(row[j]); s += ew[j]; }
        const float facw = fac_num * frcp(s);

        // fused cumsum + count + knot select
        float c = 0.0f;
        int idx = 0;
        float cw_k = -TAILB, cw_k1 = TAILB;
        bool found = false;
        #pragma unroll
        for (int j = 0; j < 7; ++j) {
            c = fmaf(ew[j], facw, c + MINSZ);
            const bool ge = (xi >= c);
            idx += ge ? 1 : 0;
            cw_k  = ge ? c : cw_k;
            cw_k1 = (!ge && !found) ? c : cw_k1;
            found = found || !ge;
        }

        // ---- heights ----
        float ch_k = -TAILB, ch_k1 = TAILB;
        {
            float eh[8];
            float sh = 0.0f;
            #pragma unroll
            for (int j = 0; j < 8; ++j) { eh[j] = __expf(row[8 + j]); sh += eh[j]; }
            const float fach = fac_num * frcp(sh);
            c = 0.0f;
            #pragma unroll
            for (int j = 1; j <= 7; ++j) {
                c = fmaf(eh[j - 1], fach, c + MINSZ);
                ch_k  = (idx == j)     ? c : ch_k;
                ch_k1 = (idx + 1 == j) ? c : ch_k1;
            }
        }

        // ---- derivatives: only the 2 needed ----
        const float d_k  = softplus_d(row[16 + idx]);
        const float d_k1 = softplus_d(row[17 + idx]);

        // ---- rational-quadratic transform ----
        const float bw  = cw_k1 - cw_k;
        const float bh  = ch_k1 - ch_k;
        const float rbw = frcp(bw);
        const float th  = (xi - cw_k) * rbw;
        const float omt = 1.0f - th;
        const float th2 = th * th;
        const float t1m = th * omt;
        const float num = bh * fmaf(d_k, th2, d_k1 * t1m);
        const float den = fmaf(2.0f * d_k1, t1m, fmaf(d_k, th2, omt * omt));
        const float out_in = fmaf(num, frcp(den), ch_k);

        const bool inside = (x >= -TAILB) && (x <= TAILB);
        __builtin_nontemporal_store(inside ? out_in : x, &out[t * 256 + tid]);

        float ldarg = d_k1 * d_k * bh * rbw;
        if (!__all(inside)) {
            const float d0 = softplus_d(row[16]);
            ldarg = inside ? ldarg : d0;
        }
        accv += __logf(ldarg);

        // all waves done reading buf[cur] before anyone stages into it
        __builtin_amdgcn_s_barrier();
    }

    // ---- one block reduction at the end ----
    float acc = accv;
    #pragma unroll
    for (int off = 32; off > 0; off >>= 1)
        acc += __shfl_down(acc, off);
    const int wave = tid >> 6, lane = tid & 63;
    if (lane == 0) wsum[wave] = acc;
    __syncthreads();
    if (tid == 0)
        partial[bid] = (wsum[0] + wsum[1]) + (wsum[2] + wsum[3]);
}

__global__ void rqs_reduce(const float* __restrict__ partial, int nb,
                           float* __restrict__ out_sum)
{
    const int tid = threadIdx.x;              // 256 threads
    double acc = 0.0;
    for (int q = tid; q < nb; q += 256)
        acc += (double)partial[q];
    #pragma unroll
    for (int off = 32; off > 0; off >>= 1)
        acc += __shfl_down(acc, off);
    __shared__ double wsum[4];
    const int wave = tid >> 6, lane = tid & 63;
    if (lane == 0) wsum[wave] = acc;
    __syncthreads();
    if (tid == 0)
        *out_sum = (float)((wsum[0] + wsum[1]) + (wsum[2] + wsum[3]));
}

extern "C" void kernel_launch(void* const* d_in, const int* in_sizes, int n_in,
                              void* d_out, int out_size, void* d_ws, size_t ws_size,
                              hipStream_t stream) {
    const float* x      = (const float*)d_in[0];
    const float* params = (const float*)d_in[1];
    float* out = (float*)d_out;
    const int n = in_sizes[0];          // 4194304
    float* partial = (float*)d_ws;      // NBLOCKS floats

    hipLaunchKernelGGL(rqs_kernel, dim3(NBLOCKS), dim3(256), 0, stream,
                       x, params, out, partial);
    hipLaunchKernelGGL(rqs_reduce, dim3(1), dim3(256), 0, stream,
                       partial, NBLOCKS, out + n);
}